// Round 7
// baseline (289.557 us; speedup 1.0000x reference)
//
#include <hip/hip_runtime.h>
#include <math.h>

typedef _Float16 f16;
typedef _Float16 f16x8 __attribute__((ext_vector_type(8)));
typedef _Float16 f16x4 __attribute__((ext_vector_type(4)));
typedef float f32x4 __attribute__((ext_vector_type(4)));
typedef float f32x8 __attribute__((ext_vector_type(8)));

#define AS1 __attribute__((address_space(1)))
#define AS3 __attribute__((address_space(3)))

__device__ __forceinline__ void gld_lds16(const f16* g, f16* l) {
#if defined(__has_builtin) && __has_builtin(__builtin_amdgcn_global_load_lds)
    __builtin_amdgcn_global_load_lds((const AS1 void*)g, (AS3 void*)l, 16, 0, 0);
#else
    *(uint4*)l = *(const uint4*)g;
#endif
}

// ---------------- pre-pass 1: input [128,256,20,20] f32 -> [128,20,20,256] f16 ----------
// Tile 32c x 64p; writes 16 B/lane (f16x8).
__global__ __launch_bounds__(256) void transpose_input(
    const float* __restrict__ inp, f16* __restrict__ out)
{
    const int b = blockIdx.x, c0 = blockIdx.y * 32, p0 = blockIdx.z * 64;
    const int tid = threadIdx.x;
    __shared__ float t[32][65];
    {
        const int p_l = tid & 63, c_l = tid >> 6;   // c_l 0..3
        const int p = p0 + p_l;
        if (p < 400) {
#pragma unroll
            for (int j = 0; j < 8; ++j) {
                int c = c_l + j * 4;
                t[c][p_l] = inp[((size_t)b * 256 + c0 + c) * 400 + p];
            }
        }
    }
    __syncthreads();
    {
        const int p_w = tid >> 2, og = tid & 3;     // p_w 0..63
        const int p = p0 + p_w;
        if (p < 400) {
            f16x8 v;
#pragma unroll
            for (int e = 0; e < 8; ++e) v[e] = (f16)t[og * 8 + e][p_w];
            *(f16x8*)(out + ((size_t)b * 400 + p) * 256 + c0 + og * 8) = v;
        }
    }
}

// ---------------- pre-pass 2: conv_w [n=256][cin=256][p=81] f32 -> w_t[n][p*256+cin] f16 -
__global__ __launch_bounds__(256) void permute_w(
    const float* __restrict__ cw, f16* __restrict__ w_t)
{
    const int n = blockIdx.x, t = threadIdx.x;
    __shared__ f16 buf[81 * 258];
    const float* src = cw + (size_t)n * 20736;
    for (int i = t; i < 20736; i += 256) {
        int cin = i / 81, p = i - cin * 81;
        buf[p * 258 + cin] = (f16)src[i];
    }
    __syncthreads();
    f16* dst = w_t + (size_t)n * 20736;
    for (int j = t; j < 20736; j += 256) {
        int p = j >> 8, cin = j & 255;
        dst[j] = buf[p * 258 + cin];
    }
}

// ---------------- conv as implicit-im2col MFMA GEMM -------------------------------------
// M=4608, N=256, K chunks of 32 f16 (648 total, ordered kh,kw,cin). Block tile 256x128,
// BK=32, wave-tile 128x64 (8x4 frags of 16x16x32 -> 32 MFMA/wave per barrier),
// double-buffered LDS 48 KB (3 blocks/CU), split-K=27 (grid 18x2x27 = 972 = 3.8/CU).
// LDS row-pair layout: pair p holds 8 chunks of 16B; ph8 = ((row&1)*4+q4) ^ (p&7).
#define SPLITK 27
#define CITER 24   // 648 / 27
__global__ __launch_bounds__(256) void conv_mfma(
    const f16* __restrict__ in_t,   // [128,20,20,256]
    const f16* __restrict__ w_t,    // [256,20736]
    f16* __restrict__ part)         // [27,4608,256] f16
{
    __shared__ f16 As[2][256 * 32];
    __shared__ f16 Bs[2][128 * 32];
    const int tid = threadIdx.x;
    const int lane = tid & 63, wave = tid >> 6;
    const int wm = wave >> 1, wn = wave & 1;
    const int m0 = blockIdx.x * 256, n0 = blockIdx.y * 128;
    const int kz = blockIdx.z;

    // staging source offsets: issue i covers pair = i*32 + (tid>>3), slot = tid&7
    int srcA[4], srcB[2];
#pragma unroll
    for (int i = 0; i < 4; ++i) {
        int pairp = i * 32 + (tid >> 3);
        int chunk8 = (tid & 7) ^ (pairp & 7);
        int e = chunk8 >> 2, q4 = chunk8 & 3;
        int m = m0 + pairp * 2 + e;
        int b = m / 36, hw = m - b * 36;
        int ho = hw / 6, wo = hw - ho * 6;
        srcA[i] = ((b * 20 + 2 * ho) * 20 + 2 * wo) * 256 + q4 * 8;
    }
#pragma unroll
    for (int i = 0; i < 2; ++i) {
        int pairp = i * 32 + (tid >> 3);
        int chunk8 = (tid & 7) ^ (pairp & 7);
        int e = chunk8 >> 2, q4 = chunk8 & 3;
        int n = n0 + pairp * 2 + e;
        srcB[i] = n * 20736 + q4 * 8;
    }

    f32x4 acc[8][4] = {};
    const int row = lane & 15, quad = lane >> 4;
    const int kc_base = kz * CITER;

    // prologue: stage chunk 0 into buf 0
    {
        int kc = kc_base;
        int p = kc >> 3, cq = kc & 7;
        int kh = p / 9, kw = p - kh * 9;
        int koffA = (kh * 20 + kw) * 256 + cq * 32;
        int koffB = kc * 32;
#pragma unroll
        for (int i = 0; i < 4; ++i)
            gld_lds16(in_t + srcA[i] + koffA, &As[0][i * 2048 + tid * 8]);
#pragma unroll
        for (int i = 0; i < 2; ++i)
            gld_lds16(w_t + srcB[i] + koffB, &Bs[0][i * 2048 + tid * 8]);
    }

    for (int it = 0; it < CITER; ++it) {
        const int cur = it & 1;
        __syncthreads();
        if (it + 1 < CITER) {
            int kc = kc_base + it + 1;
            int p = kc >> 3, cq = kc & 7;
            int kh = p / 9, kw = p - kh * 9;
            int koffA = (kh * 20 + kw) * 256 + cq * 32;
            int koffB = kc * 32;
#pragma unroll
            for (int i = 0; i < 4; ++i)
                gld_lds16(in_t + srcA[i] + koffA, &As[cur ^ 1][i * 2048 + tid * 8]);
#pragma unroll
            for (int i = 0; i < 2; ++i)
                gld_lds16(w_t + srcB[i] + koffB, &Bs[cur ^ 1][i * 2048 + tid * 8]);
        }
        f16x8 af[8], bf[4];
#pragma unroll
        for (int mt = 0; mt < 8; ++mt) {
            int m = wm * 128 + mt * 16 + row;
            int ph8 = (((m & 1) << 2) + quad) ^ ((m >> 1) & 7);
            af[mt] = *(const f16x8*)(&As[cur][(m >> 1) * 64 + ph8 * 8]);
        }
#pragma unroll
        for (int nt = 0; nt < 4; ++nt) {
            int n = wn * 64 + nt * 16 + row;
            int ph8 = (((n & 1) << 2) + quad) ^ ((n >> 1) & 7);
            bf[nt] = *(const f16x8*)(&Bs[cur][(n >> 1) * 64 + ph8 * 8]);
        }
#pragma unroll
        for (int mt = 0; mt < 8; ++mt)
#pragma unroll
            for (int nt = 0; nt < 4; ++nt)
                acc[mt][nt] = __builtin_amdgcn_mfma_f32_16x16x32_f16(
                    af[mt], bf[nt], acc[mt][nt], 0, 0, 0);
    }

    // epilogue: f16 stores to partial buffer
    const int col = lane & 15, qr = (lane >> 4) * 4;
    f16* pb = part + (size_t)kz * 4608 * 256;
#pragma unroll
    for (int mt = 0; mt < 8; ++mt)
#pragma unroll
        for (int rg = 0; rg < 4; ++rg) {
            int m = m0 + wm * 128 + mt * 16 + qr + rg;
#pragma unroll
            for (int nt = 0; nt < 4; ++nt) {
                int n = n0 + wn * 64 + nt * 16 + col;
                pb[(size_t)m * 256 + n] = (f16)acc[mt][nt][rg];
            }
        }
}

// ---------------- split-K reduce + bias + capsule squash -> x[128,1152,8] ---------------
__global__ __launch_bounds__(256) void combine_squash(
    const f16* __restrict__ part, const float* __restrict__ bias,
    float* __restrict__ x)
{
    int idx = blockIdx.x * 256 + threadIdx.x;   // over 4608*32
    int m = idx >> 5, o = idx & 31;
    int b = m / 36, hw = m - b * 36;
    float val[8];
#pragma unroll
    for (int k = 0; k < 8; ++k) val[k] = bias[k * 32 + o];
#pragma unroll
    for (int s = 0; s < SPLITK; ++s) {
        const f16* p = part + ((size_t)s * 4608 + m) * 256 + o;
#pragma unroll
        for (int k = 0; k < 8; ++k) val[k] += (float)p[k * 32];
    }
    float sn = 0.f;
#pragma unroll
    for (int k = 0; k < 8; ++k) sn += val[k] * val[k];
    float scale = sqrtf(sn) / (1.f + sn);
    int r = o * 36 + hw;
    float* xp = x + ((size_t)b * 1152 + r) * 8;
#pragma unroll
    for (int k = 0; k < 8; ++k) xp[k] = val[k] * scale;
}

// ---------------- pred (f16) + fused routing-iter-0 s-accumulation ----------------------
// thread = (r = r0 + tid>>2, og = tid&3): 4 o-outputs; rw read as float4 (16 B/lane).
// s0[c,b,o] += sum_r pred[c,b,r,o]  (iter-0 e=1; z0=1152 via z_in==null downstream).
__global__ __launch_bounds__(256) void pred_s0(
    const float* __restrict__ x, const float* __restrict__ rw,
    f16* __restrict__ pred, float* __restrict__ s0)
{
    const int c = blockIdx.x, r0 = blockIdx.y * 64, b0 = blockIdx.z * 32;
    const int tid = threadIdx.x;
    const int og = tid & 3, rl = tid >> 2;       // rl 0..63
    const int r = r0 + rl;

    __shared__ float s_sh[32 * 16];
    __shared__ float xs[64][8];
    s_sh[tid] = 0.f; s_sh[tid + 256] = 0.f;

    float W[8][4];
    {
        const float* wb = rw + ((size_t)(c * 1152 + r) * 8) * 16 + og * 4;
#pragma unroll
        for (int k = 0; k < 8; ++k) {
            float4 w4 = *(const float4*)(wb + k * 16);
            W[k][0] = w4.x; W[k][1] = w4.y; W[k][2] = w4.z; W[k][3] = w4.w;
        }
    }

    for (int bb = 0; bb < 32; ++bb) {
        const int b = b0 + bb;
        __syncthreads();
        if (tid < 128)
            *(float4*)&xs[tid >> 1][(tid & 1) * 4] =
                *(const float4*)(x + ((size_t)b * 1152 + r0 + (tid >> 1)) * 8 + (tid & 1) * 4);
        __syncthreads();

        float p[4];
        {
            const float* xr = xs[rl];
#pragma unroll
            for (int j = 0; j < 4; ++j) p[j] = xr[0] * W[0][j];
#pragma unroll
            for (int k = 1; k < 8; ++k)
#pragma unroll
                for (int j = 0; j < 4; ++j) p[j] += xr[k] * W[k][j];
        }
        {
            f16x4 pv;
#pragma unroll
            for (int j = 0; j < 4; ++j) pv[j] = (f16)p[j];
            *(f16x4*)(pred + ((size_t)(c * 128 + b) * 1152 + r) * 16 + og * 4) = pv;
        }
        // reduce over the wave's 16 r values (lane bits 2..5), all lanes end with sum
#pragma unroll
        for (int j = 0; j < 4; ++j) {
            float v = p[j];
            v += __shfl_xor(v, 4);
            v += __shfl_xor(v, 8);
            v += __shfl_xor(v, 16);
            v += __shfl_xor(v, 32);
            if ((tid & 63) < 4) atomicAdd(&s_sh[bb * 16 + og * 4 + j], v);
        }
    }
    __syncthreads();
    for (int i = tid; i < 512; i += 256)
        atomicAdd(&s0[((size_t)c * 128 + b0 + (i >> 4)) * 16 + (i & 15)], s_sh[i]);
}

// ---------------- routing iteration with inline batch-squash ----------------------------
// v_prev computed inline from s_in/z_in (squash over batch axis; z_in==null -> 1/1152),
// a_new = (a_in?a_in:0)+pred.v_prev, e=exp(a_new), optional a_out.
// Writes s_out[c,b,16] (unnormalized sum e*pred) and z_out[c,b] (sum e).
__global__ __launch_bounds__(256) void route_f16(
    const f16* __restrict__ pred, const float* __restrict__ s_in,
    const float* __restrict__ z_in, const float* __restrict__ a_in,
    float* __restrict__ a_out, float* __restrict__ s_out, float* __restrict__ z_out)
{
    const int c = blockIdx.x, b = blockIdx.y, tid = threadIdx.x;
    const size_t base = (size_t)(c * 128 + b) * 1152;

    __shared__ float vs[16];
    __shared__ float mat[128][17];
    __shared__ float red[256][16];
    __shared__ float red2[16][16];
    __shared__ float zred[256];
    __shared__ float zpart[16];

    {   // inline squash(s_prev/z_prev, axis=batch) -> v_prev for this (c,b)
        if (tid < 128) {
            float zin = z_in ? 1.f / z_in[c * 128 + tid] : (1.f / 1152.f);
            const float* sp = s_in + (size_t)(c * 128 + tid) * 16;
#pragma unroll
            for (int o = 0; o < 16; ++o) mat[tid][o] = sp[o] * zin;
        }
        __syncthreads();
        if (tid < 16) {
            float sn = 0.f;
            for (int i = 0; i < 128; ++i) { float q = mat[i][tid]; sn += q * q; }
            vs[tid] = mat[b][tid] * sqrtf(sn) / (1.f + sn);
        }
        __syncthreads();
    }

    float sacc[16];
#pragma unroll
    for (int o = 0; o < 16; ++o) sacc[o] = 0.f;
    float zacc = 0.f;

    for (int r = tid; r < 1152; r += 256) {
        const f16x8* pp = (const f16x8*)(pred + (base + r) * 16);
        f32x8 q0 = __builtin_convertvector(pp[0], f32x8);
        f32x8 q1 = __builtin_convertvector(pp[1], f32x8);
        float contrib = 0.f;
#pragma unroll
        for (int j = 0; j < 8; ++j) contrib += q0[j] * vs[j] + q1[j] * vs[j + 8];
        float an = contrib + (a_in ? a_in[base + r] : 0.f);
        if (a_out) a_out[base + r] = an;
        float e = __expf(an);
#pragma unroll
        for (int j = 0; j < 8; ++j) { sacc[j] += e * q0[j]; sacc[j + 8] += e * q1[j]; }
        zacc += e;
    }

#pragma unroll
    for (int o = 0; o < 16; ++o) red[tid][o] = sacc[o];
    zred[tid] = zacc;
    __syncthreads();
    {
        const int o = tid & 15, seg = tid >> 4;
        float t = 0.f;
#pragma unroll
        for (int j = 0; j < 16; ++j) t += red[seg * 16 + j][o];
        red2[seg][o] = t;
        if (tid < 16) {
            float tz = 0.f;
#pragma unroll
            for (int j = 0; j < 16; ++j) tz += zred[tid * 16 + j];
            zpart[tid] = tz;
        }
    }
    __syncthreads();
    if (tid < 16) {
        float t = 0.f;
#pragma unroll
        for (int seg = 0; seg < 16; ++seg) t += red2[seg][tid];
        s_out[(size_t)(c * 128 + b) * 16 + tid] = t;
    } else if (tid == 16) {
        float tz = 0.f;
#pragma unroll
        for (int j = 0; j < 16; ++j) tz += zpart[j];
        z_out[c * 128 + b] = tz;
    }
}

// ---------------- final: v = squash(s/z, axis=batch) -> out[b,c,o] ----------------------
__global__ __launch_bounds__(128) void squash_final(
    const float* __restrict__ s, const float* __restrict__ z,
    float* __restrict__ out)
{
    const int c = blockIdx.x, b = threadIdx.x;   // 10 blocks, 128 threads
    float sv[16];
    const float* sp = s + ((size_t)c * 128 + b) * 16;
    float zin = 1.f / z[c * 128 + b];
#pragma unroll
    for (int o = 0; o < 16; ++o) sv[o] = sp[o] * zin;
    __shared__ float m[16][129];
#pragma unroll
    for (int o = 0; o < 16; ++o) m[o][b] = sv[o] * sv[o];
    __syncthreads();
    __shared__ float sn[16];
    if (b < 16) {
        float t = 0.f;
        for (int i = 0; i < 128; ++i) t += m[b][i];
        sn[b] = t;
    }
    __syncthreads();
#pragma unroll
    for (int o = 0; o < 16; ++o) {
        float scale = sqrtf(sn[o]) / (1.f + sn[o]);
        out[((size_t)b * 10 + c) * 16 + o] = sv[o] * scale;
    }
}

// ---------------- launch ----------------------------------------------------------------
extern "C" void kernel_launch(void* const* d_in, const int* in_sizes, int n_in,
                              void* d_out, int out_size, void* d_ws, size_t ws_size,
                              hipStream_t stream)
{
    (void)in_sizes; (void)n_in; (void)out_size; (void)ws_size;
    const float* inp = (const float*)d_in[0];
    const float* cw  = (const float*)d_in[1];
    const float* cb  = (const float*)d_in[2];
    const float* rw  = (const float*)d_in[3];
    float* out = (float*)d_out;

    // workspace layout (bytes), total ~111.3 MB:
    //   [0, 63.7M)   part f16 [27,4608,256]  -> dead after combine
    //   [0, 47.2M)   pred f16 [10,128,1152,16] (aliases part)
    //   [63.7M, ..)  x, a, s/z buffers
    //   [74.5M, ..)  in_t, w_t (conv-time only)
    char* ws = (char*)d_ws;
    f16*   part = (f16*)(ws);                    // 63,700,992
    f16*   pred = (f16*)(ws);                    // 47,185,920 (alias)
    float* x    = (float*)(ws + 63700992);       //  4,718,592
    float* a    = (float*)(ws + 68419584);       //  5,898,240
    float* sA   = (float*)(ws + 74317824);       //     81,920
    float* zA   = (float*)(ws + 74399744);       //      5,120
    float* sB   = (float*)(ws + 74404864);       //     81,920
    float* zB   = (float*)(ws + 74486784);       //      5,120
    f16*   in_t = (f16*)(ws + 74491904);         // 26,214,400
    f16*   w_t  = (f16*)(ws + 100706304);        // 10,616,832 -> end 111,323,136

    transpose_input<<<dim3(128, 8, 7), 256, 0, stream>>>(inp, in_t);
    permute_w<<<256, 256, 0, stream>>>(cw, w_t);
    conv_mfma<<<dim3(18, 2, SPLITK), 256, 0, stream>>>(in_t, w_t, part);
    combine_squash<<<576, 256, 0, stream>>>(part, cb, x);

    hipMemsetAsync(sA, 0, 81920, stream);
    pred_s0<<<dim3(10, 18, 4), 256, 0, stream>>>(x, rw, pred, sA);   // pred + iter0 s

    route_f16<<<dim3(10, 128), 256, 0, stream>>>(pred, sA, nullptr, nullptr,
                                                 a, sB, zB);          // iter 1 (z0=1152)
    route_f16<<<dim3(10, 128), 256, 0, stream>>>(pred, sB, zB, a,
                                                 nullptr, sA, zA);    // iter 2
    squash_final<<<10, 128, 0, stream>>>(sA, zA, out);
}